// Round 8
// baseline (442.094 us; speedup 1.0000x reference)
//
#include <hip/hip_runtime.h>

#define T_ 8
#define N_ 10000
#define E_ 160000
#define G_ 32
#define C_ 10
#define F_ 128

typedef _Float16 f16;
typedef _Float16 f16x2 __attribute__((ext_vector_type(2)));
typedef _Float16 f16x4 __attribute__((ext_vector_type(4)));
typedef _Float16 f16x8 __attribute__((ext_vector_type(8)));
typedef float floatx4 __attribute__((ext_vector_type(4)));

static constexpr size_t ROWS = (size_t)T_ * N_;   // 80000

// ---------------- workspace layout (bytes) ----------------
// R8: all histogram/CSR atomics moved to LDS (build_kernel); no global atomics,
// no zero-init memset needed anywhere.
static constexpr size_t OFF_XH    = 0;          // f16 [80000][128] X' = dinv*X (reused as H2)
static constexpr size_t OFF_A1    = 20480000;   // f16 [80000][128] (reused as A2)
static constexpr size_t OFF_H1    = 40960000;   // f16 [80000][128] H1' = dinv*H1
static constexpr size_t OFF_REC   = 61440000;   // int [T][E] src (position-in-row arbitrary)
static constexpr size_t OFF_DINV  = 66560000;   // float [T][N]
static constexpr size_t OFF_RP    = 66880000;   // int [T][N+1]
static constexpr size_t OFF_WP    = 67200032;   // f16 packed W1,W2 (2*16384)
static constexpr size_t OFF_BRP   = 67265568;   // int [T*G+1]
static constexpr size_t OFF_BLIST = 67266624;   // int [80000]
static constexpr size_t OFF_EMBH  = 67586624;   // f16 [256][128]
static constexpr size_t OFF_GPACK = 67652160;   // f16 4*49152 packed GRU weights
static constexpr size_t OFF_GI0   = 68045376;   // float [256][384]
// end ~68.4 MB

// ---------------- fast gates (v_exp_f32 / v_rcp_f32, ~1 ulp) ----------------
__device__ __forceinline__ float sig_fast(float x) {
  return __builtin_amdgcn_rcpf(1.0f + __builtin_amdgcn_exp2f(-1.4426950408889634f * x));
}
__device__ __forceinline__ float tanh_fast(float x) {
  return 1.0f - 2.0f * __builtin_amdgcn_rcpf(1.0f + __builtin_amdgcn_exp2f(2.8853900817779268f * x));
}

// ---------------- build: per-t CSR + dinv + batch-CSR, all atomics in LDS ----------------
__global__ __launch_bounds__(1024) void build_kernel(
    const int* __restrict__ ei, const int* __restrict__ batch,
    int* __restrict__ rp, float* __restrict__ dinv,
    int* __restrict__ rec, int* __restrict__ brp, int* __restrict__ blist) {
  __shared__ int degL[N_];                      // 40 KB: hist -> excl scan -> running offset
  __shared__ int wsum[16];
  __shared__ int carry;
  __shared__ int cntL[G_];
  __shared__ int cbase[G_];
  int t = blockIdx.x, tid = threadIdx.x, lane = tid & 63, wid = tid >> 6;
  for (int i = tid; i < N_; i += 1024) degL[i] = 0;
  if (tid < G_) cntL[tid] = 0;
  if (tid == 0) carry = 0;
  __syncthreads();
  const int* srcp = ei + (size_t)t * 2 * E_;
  const int* dstp = srcp + E_;
  // pass 1: degree histogram (int4 streamed; 40000 int4 slots cover E exactly)
  for (int e0 = tid * 4; e0 + 3 < E_; e0 += 4096) {
    int4 d = *(const int4*)(dstp + e0);
    atomicAdd(&degL[d.x], 1); atomicAdd(&degL[d.y], 1);
    atomicAdd(&degL[d.z], 1); atomicAdd(&degL[d.w], 1);
  }
  // batch histogram
  for (int n = tid; n < N_; n += 1024) atomicAdd(&cntL[batch[t * N_ + n]], 1);
  __syncthreads();
  // dinv (must read degL before scan overwrites it)
  for (int n = tid; n < N_; n += 1024)
    dinv[t * N_ + n] = rsqrtf((float)degL[n] + 1.0f);
  if (tid == 0) rp[t * (N_ + 1)] = 0;
  __syncthreads();
  // in-place exclusive scan of degL; inclusive -> global rp
  for (int c0 = 0; c0 < N_; c0 += 1024) {
    int i = c0 + tid;
    int v0 = (i < N_) ? degL[i] : 0;
    int v = v0;
    for (int ofs = 1; ofs < 64; ofs <<= 1) {
      int u = __shfl_up(v, ofs);
      if (lane >= ofs) v += u;
    }
    if (lane == 63) wsum[wid] = v;
    __syncthreads();
    if (wid == 0) {
      int w = (lane < 16) ? wsum[lane] : 0;
      for (int ofs = 1; ofs < 16; ofs <<= 1) {
        int u = __shfl_up(w, ofs);
        if (lane >= ofs) w += u;
      }
      if (lane < 16) wsum[lane] = w;
    }
    __syncthreads();
    int base = carry + (wid ? wsum[wid - 1] : 0);
    if (i < N_) {
      rp[t * (N_ + 1) + i + 1] = base + v;
      degL[i] = base + v - v0;                  // exclusive -> running fill offset
    }
    __syncthreads();
    if (tid == 0) carry += wsum[15];
    __syncthreads();
  }
  // group-count exclusive scan (wave 0), brp global (+32 entry overlaps next t: same value)
  if (wid == 0) {
    int v0 = (lane < G_) ? cntL[lane] : 0;
    int v = v0;
    for (int ofs = 1; ofs < 32; ofs <<= 1) {
      int u = __shfl_up(v, ofs);
      if (lane >= ofs) v += u;
    }
    if (lane < G_) {
      cbase[lane] = v - v0;
      brp[t * G_ + lane] = t * N_ + (v - v0);
    }
    if (lane == 0) brp[t * G_ + G_] = t * N_ + N_;
  }
  __syncthreads();
  // pass 2: CSR fill via LDS running offsets
  for (int e0 = tid * 4; e0 + 3 < E_; e0 += 4096) {
    int4 s = *(const int4*)(srcp + e0);
    int4 d = *(const int4*)(dstp + e0);
    int p0 = atomicAdd(&degL[d.x], 1);
    int p1 = atomicAdd(&degL[d.y], 1);
    int p2 = atomicAdd(&degL[d.z], 1);
    int p3 = atomicAdd(&degL[d.w], 1);
    int* rt = rec + (size_t)t * E_;
    rt[p0] = s.x; rt[p1] = s.y; rt[p2] = s.z; rt[p3] = s.w;
  }
  __syncthreads();
  // batch-CSR fill
  for (int n = tid; n < N_; n += 1024) {
    int g = batch[t * N_ + n];
    int p = atomicAdd(&cbase[g], 1);
    blist[t * N_ + p] = t * N_ + n;
  }
}

// ---------------- fp32 -> fp16 convert, pre-scaled: X' = dinv[row] * x ----------------
__global__ void cvt_kernel(const float* __restrict__ x, const float* __restrict__ dinv,
                           f16* __restrict__ xh) {
  size_t i = ((size_t)blockIdx.x * 256 + threadIdx.x) * 4;
  float4 v = *(const float4*)(x + i);
  float d = dinv[i >> 7];
  f16x4 o; o.x = (f16)(v.x * d); o.y = (f16)(v.y * d);
  o.z = (f16)(v.z * d); o.w = (f16)(v.w * d);
  *(f16x4*)(xh + i) = o;
}

// ---------------- aggregation: out = dinv[row]*(sum X'[src] + X'[row]) ----------------
// XCD-swizzled (t = blk&7); CSR index stream software-pipelined one unroll ahead
// so idx-load latency overlaps the dependent gathers.
__global__ void agg_kernel(const f16* __restrict__ X, f16* __restrict__ A,
                           const int* __restrict__ rp, const int* __restrict__ rec,
                           const float* __restrict__ dinv) {
  int wave = threadIdx.x >> 6, lane = threadIdx.x & 63;
  int b = blockIdx.x;
  int t = b & 7, i = b >> 3;
  int n = i * 4 + wave;
  int row = t * N_ + n;
  float ds = dinv[row];
  f16x2 xv = *(const f16x2*)(X + (size_t)row * F_ + 2 * lane);
  float a00 = (float)xv.x, a01 = (float)xv.y;   // self term (X' already has one dinv)
  float a10 = 0.f, a11 = 0.f, a20 = 0.f, a21 = 0.f, a30 = 0.f, a31 = 0.f;
  int beg = rp[t * (N_ + 1) + n], end = rp[t * (N_ + 1) + n + 1];
  beg = __builtin_amdgcn_readfirstlane(beg);
  end = __builtin_amdgcn_readfirstlane(end);
  const int* rc = rec + (size_t)t * E_;
  const f16* Xt = X + (size_t)t * N_ * F_;
  int e = beg;
  int i0 = 0, i1 = 0, i2 = 0, i3 = 0;
  if (e + 3 < end) { i0 = rc[e]; i1 = rc[e + 1]; i2 = rc[e + 2]; i3 = rc[e + 3]; }
  for (; e + 7 < end; e += 4) {
    int n0 = rc[e + 4], n1 = rc[e + 5], n2 = rc[e + 6], n3 = rc[e + 7];
    f16x2 h0 = *(const f16x2*)(Xt + (size_t)i0 * F_ + 2 * lane);
    f16x2 h1 = *(const f16x2*)(Xt + (size_t)i1 * F_ + 2 * lane);
    f16x2 h2 = *(const f16x2*)(Xt + (size_t)i2 * F_ + 2 * lane);
    f16x2 h3 = *(const f16x2*)(Xt + (size_t)i3 * F_ + 2 * lane);
    a00 += (float)h0.x; a01 += (float)h0.y;
    a10 += (float)h1.x; a11 += (float)h1.y;
    a20 += (float)h2.x; a21 += (float)h2.y;
    a30 += (float)h3.x; a31 += (float)h3.y;
    i0 = n0; i1 = n1; i2 = n2; i3 = n3;
  }
  if (e + 3 < end) {
    f16x2 h0 = *(const f16x2*)(Xt + (size_t)i0 * F_ + 2 * lane);
    f16x2 h1 = *(const f16x2*)(Xt + (size_t)i1 * F_ + 2 * lane);
    f16x2 h2 = *(const f16x2*)(Xt + (size_t)i2 * F_ + 2 * lane);
    f16x2 h3 = *(const f16x2*)(Xt + (size_t)i3 * F_ + 2 * lane);
    a00 += (float)h0.x; a01 += (float)h0.y;
    a10 += (float)h1.x; a11 += (float)h1.y;
    a20 += (float)h2.x; a21 += (float)h2.y;
    a30 += (float)h3.x; a31 += (float)h3.y;
    e += 4;
  }
  for (; e < end; ++e) {
    int s = rc[e];
    f16x2 hv = *(const f16x2*)(Xt + (size_t)s * F_ + 2 * lane);
    a00 += (float)hv.x; a01 += (float)hv.y;
  }
  float r0 = ds * ((a00 + a10) + (a20 + a30));
  float r1 = ds * ((a01 + a11) + (a21 + a31));
  f16x2 o; o.x = (f16)r0; o.y = (f16)r1;
  *(f16x2*)(A + (size_t)row * F_ + 2 * lane) = o;
}

// ---------------- pack W1/W2 + GRU weights into MFMA B-frag layout (merged) ----------------
__global__ void packall_kernel(const float* __restrict__ W1, const float* __restrict__ W2,
                               f16* __restrict__ Wp,
                               const float* __restrict__ A0, const float* __restrict__ A1,
                               const float* __restrict__ A2, const float* __restrict__ A3,
                               f16* __restrict__ gp) {
  int idx = blockIdx.x * 256 + threadIdx.x;     // < 896*256 = 229376
  if (idx < 32768) {
    const float* W = (idx < 16384) ? W1 : W2;
    int l = idx & 16383;
    int j = l & 7, lane = (l >> 3) & 63, ct = (l >> 9) & 7, kc = (l >> 12) & 3;
    int k = kc * 32 + ((lane >> 4) & 3) * 8 + j;
    int n = ct * 16 + (lane & 15);
    Wp[idx] = (f16)W[k * 128 + n];
  } else {
    int gidx = idx - 32768;                     // < 196608
    int mat = gidx / 49152, l = gidx - mat * 49152;
    int j = l & 7, lane = (l >> 3) & 63, kc = (l >> 9) & 3, nt = l >> 11;
    int k = kc * 32 + ((lane >> 4) & 3) * 8 + j;
    int u = nt * 16 + (lane & 15);
    const float* W = (mat == 0) ? A0 : (mat == 1) ? A1 : (mat == 2) ? A2 : A3;
    gp[gidx] = (f16)W[u * 128 + k];
  }
}

// ---------------- GEMM: O = relu(A @ W + b) [* dinv-row scale], MFMA 16x16x32 ----------------
__global__ __launch_bounds__(256) void gemm_kernel(const f16* __restrict__ A,
                                                   const f16* __restrict__ Wp,
                                                   const float* __restrict__ bias,
                                                   const float* __restrict__ scale,
                                                   f16* __restrict__ O) {
  __shared__ f16x8 Bp[2048];                    // 32 KB packed W
  const f16x8* Wv = (const f16x8*)Wp;
  for (int i = threadIdx.x; i < 2048; i += 256) Bp[i] = Wv[i];
  __syncthreads();
  int wave = threadIdx.x >> 6, lane = threadIdx.x & 63;
  int quad = lane >> 4, m = lane & 15;
  int rowbase = blockIdx.x * 64 + wave * 16;
  const f16x8* Arow = (const f16x8*)(A + (size_t)(rowbase + m) * F_);
  floatx4 acc[8];
#pragma unroll
  for (int ct = 0; ct < 8; ++ct) { floatx4 z = {0.f, 0.f, 0.f, 0.f}; acc[ct] = z; }
#pragma unroll
  for (int kc = 0; kc < 4; ++kc) {
    f16x8 a = Arow[kc * 4 + quad];
#pragma unroll
    for (int ct = 0; ct < 8; ++ct)
      acc[ct] = __builtin_amdgcn_mfma_f32_16x16x32_f16(a, Bp[(kc * 8 + ct) * 64 + lane],
                                                       acc[ct], 0, 0, 0);
  }
  float sv[4];
#pragma unroll
  for (int r = 0; r < 4; ++r)
    sv[r] = scale ? scale[rowbase + quad * 4 + r] : 1.0f;
#pragma unroll
  for (int ct = 0; ct < 8; ++ct) {
    int colc = ct * 16 + m;
    float bv = bias[colc];
#pragma unroll
    for (int r = 0; r < 4; ++r) {
      int row = rowbase + quad * 4 + r;
      float v = fmaxf(acc[ct][r] + bv, 0.0f) * sv[r];
      O[(size_t)row * F_ + colc] = (f16)v;
    }
  }
}

// ---------------- pooling via batch-CSR gather -> f16 emb ----------------
__global__ void pool_kernel(const f16* __restrict__ H, const int* __restrict__ brp,
                            const int* __restrict__ blist, f16* __restrict__ embh) {
  int wave = threadIdx.x >> 6, lane = threadIdx.x & 63;
  int idx = blockIdx.x * 4 + wave;              // t*G+g, < 256
  int beg = brp[idx], end = brp[idx + 1];
  beg = __builtin_amdgcn_readfirstlane(beg);
  end = __builtin_amdgcn_readfirstlane(end);
  float a00 = 0.f, a01 = 0.f, a10 = 0.f, a11 = 0.f;
  float a20 = 0.f, a21 = 0.f, a30 = 0.f, a31 = 0.f;
  int e = beg;
  for (; e + 3 < end; e += 4) {
    int r0 = blist[e], r1 = blist[e + 1], r2 = blist[e + 2], r3 = blist[e + 3];
    f16x2 v0 = *(const f16x2*)(H + (size_t)r0 * F_ + 2 * lane);
    f16x2 v1 = *(const f16x2*)(H + (size_t)r1 * F_ + 2 * lane);
    f16x2 v2 = *(const f16x2*)(H + (size_t)r2 * F_ + 2 * lane);
    f16x2 v3 = *(const f16x2*)(H + (size_t)r3 * F_ + 2 * lane);
    a00 += (float)v0.x; a01 += (float)v0.y;
    a10 += (float)v1.x; a11 += (float)v1.y;
    a20 += (float)v2.x; a21 += (float)v2.y;
    a30 += (float)v3.x; a31 += (float)v3.y;
  }
  for (; e < end; ++e) {
    int r = blist[e];
    f16x2 v = *(const f16x2*)(H + (size_t)r * F_ + 2 * lane);
    a00 += (float)v.x; a01 += (float)v.y;
  }
  float d = 1.0f / fmaxf((float)(end - beg), 1.0f);
  f16x2 o;
  o.x = (f16)(((a00 + a10) + (a20 + a30)) * d);
  o.y = (f16)(((a01 + a11) + (a21 + a31)) * d);
  *(f16x2*)(embh + (size_t)idx * F_ + 2 * lane) = o;
}

// ---------------- gi0 = emb @ Wih0^T : M=256, K=128, N=384 ----------------
__global__ __launch_bounds__(256) void gi0_kernel(const f16* __restrict__ embh,
                                                  const f16* __restrict__ gp,
                                                  float* __restrict__ gi0) {
  int wave = threadIdx.x >> 6, lane = threadIdx.x & 63;
  int quad = lane >> 4, mm = lane & 15;
  int rowbase = blockIdx.x * 64 + wave * 16;    // grid 4
  const f16* Arow = embh + (size_t)(rowbase + mm) * 128;
  floatx4 acc[24];
#pragma unroll
  for (int nt = 0; nt < 24; ++nt) { floatx4 z = {0.f, 0.f, 0.f, 0.f}; acc[nt] = z; }
#pragma unroll
  for (int kc = 0; kc < 4; ++kc) {
    f16x8 a = *(const f16x8*)(Arow + kc * 32 + quad * 8);
#pragma unroll
    for (int nt = 0; nt < 24; ++nt) {
      f16x8 b = *(const f16x8*)(gp + (size_t)(((nt * 4 + kc) * 64 + lane)) * 8);
      acc[nt] = __builtin_amdgcn_mfma_f32_16x16x32_f16(a, b, acc[nt], 0, 0, 0);
    }
  }
#pragma unroll
  for (int nt = 0; nt < 24; ++nt)
#pragma unroll
    for (int r = 0; r < 4; ++r)
      gi0[(size_t)(rowbase + quad * 4 + r) * 384 + nt * 16 + mm] = acc[nt][r];
}

// ---------------- fused 2-layer GRU + final linear: 16 blocks x 2 groups ----------------
__global__ __launch_bounds__(256, 1) void gru_fused(
    const f16* __restrict__ gp, const float* __restrict__ gi0,
    const float* __restrict__ bih0, const float* __restrict__ bhh0,
    const float* __restrict__ bih1, const float* __restrict__ bhh1,
    const float* __restrict__ Wc, const float* __restrict__ bc,
    float* __restrict__ out) {
  __shared__ f16 hb0[16 * 136];
  __shared__ f16 hb1[16 * 136];
  __shared__ float ghb[2 * 384];
  __shared__ float gib[2 * 384];
  __shared__ float h1s[2 * 128];
  int tid = threadIdx.x, wave = tid >> 6, lane = tid & 63;
  int quad = lane >> 4, mm = lane & 15;
  int g2 = tid >> 7, f = tid & 127;
  int bid = blockIdx.x;

  f16x8 B0[24], B1[24];
#pragma unroll
  for (int i = 0; i < 6; ++i)
#pragma unroll
    for (int kc = 0; kc < 4; ++kc) {
      size_t off = (size_t)((((wave * 6 + i) * 4 + kc) * 64 + lane)) * 8;
      B0[i * 4 + kc] = *(const f16x8*)(gp + 1 * 49152 + off);
      B1[i * 4 + kc] = *(const f16x8*)(gp + 3 * 49152 + off);
    }
  float br0 = bih0[f] + bhh0[f];
  float bz0 = bih0[128 + f] + bhh0[128 + f];
  float bni0 = bih0[256 + f], bnh0 = bhh0[256 + f];
  float br1 = bih1[f] + bhh1[f];
  float bz1 = bih1[128 + f] + bhh1[128 + f];
  float bni1 = bih1[256 + f], bnh1 = bhh1[256 + f];

  for (int i = tid; i < 16 * 136; i += 256) { hb0[i] = (f16)0.f; hb1[i] = (f16)0.f; }
  float h0 = 0.f, h1 = 0.f;
  __syncthreads();

  const f16* wih1 = gp + 2 * 49152;
  for (int t = 0; t < T_; ++t) {
    f16x8 Bs[24];
#pragma unroll
    for (int i = 0; i < 6; ++i)
#pragma unroll
      for (int kc = 0; kc < 4; ++kc)
        Bs[i * 4 + kc] = *(const f16x8*)(wih1 +
            (size_t)((((wave * 6 + i) * 4 + kc) * 64 + lane)) * 8);
    const float* gi = gi0 + (size_t)(t * G_ + bid * 2 + g2) * 384;
    float gir = gi[f], giz = gi[128 + f], gin = gi[256 + f];

    floatx4 acc[6];
#pragma unroll
    for (int i = 0; i < 6; ++i) { floatx4 z = {0.f, 0.f, 0.f, 0.f}; acc[i] = z; }
#pragma unroll
    for (int kc = 0; kc < 4; ++kc) {
      f16x8 a = *(const f16x8*)(hb0 + mm * 136 + kc * 32 + quad * 8);
#pragma unroll
      for (int i = 0; i < 6; ++i)
        acc[i] = __builtin_amdgcn_mfma_f32_16x16x32_f16(a, B0[i * 4 + kc], acc[i], 0, 0, 0);
    }
    if (quad == 0) {
#pragma unroll
      for (int i = 0; i < 6; ++i) {
        ghb[0 * 384 + wave * 96 + i * 16 + mm] = acc[i][0];
        ghb[1 * 384 + wave * 96 + i * 16 + mm] = acc[i][1];
      }
    }
    __syncthreads();

    {
      float hr = ghb[g2 * 384 + f];
      float hz = ghb[g2 * 384 + 128 + f];
      float hn = ghb[g2 * 384 + 256 + f];
      float r = sig_fast(gir + hr + br0);
      float z = sig_fast(giz + hz + bz0);
      float nn = tanh_fast(gin + bni0 + r * (hn + bnh0));
      h0 = (1.0f - z) * nn + z * h0;
      hb0[g2 * 136 + f] = (f16)h0;
    }
    __syncthreads();

    floatx4 accx[6], acch[6];
#pragma unroll
    for (int i = 0; i < 6; ++i) {
      floatx4 z = {0.f, 0.f, 0.f, 0.f}; accx[i] = z; acch[i] = z;
    }
#pragma unroll
    for (int kc = 0; kc < 4; ++kc) {
      f16x8 ax = *(const f16x8*)(hb0 + mm * 136 + kc * 32 + quad * 8);
      f16x8 ah = *(const f16x8*)(hb1 + mm * 136 + kc * 32 + quad * 8);
#pragma unroll
      for (int i = 0; i < 6; ++i) {
        accx[i] = __builtin_amdgcn_mfma_f32_16x16x32_f16(ax, Bs[i * 4 + kc], accx[i], 0, 0, 0);
        acch[i] = __builtin_amdgcn_mfma_f32_16x16x32_f16(ah, B1[i * 4 + kc], acch[i], 0, 0, 0);
      }
    }
    if (quad == 0) {
#pragma unroll
      for (int i = 0; i < 6; ++i) {
        gib[0 * 384 + wave * 96 + i * 16 + mm] = accx[i][0];
        gib[1 * 384 + wave * 96 + i * 16 + mm] = accx[i][1];
        ghb[0 * 384 + wave * 96 + i * 16 + mm] = acch[i][0];
        ghb[1 * 384 + wave * 96 + i * 16 + mm] = acch[i][1];
      }
    }
    __syncthreads();

    {
      float i1r = gib[g2 * 384 + f];
      float i1z = gib[g2 * 384 + 128 + f];
      float i1n = gib[g2 * 384 + 256 + f];
      float hr = ghb[g2 * 384 + f];
      float hz = ghb[g2 * 384 + 128 + f];
      float hn = ghb[g2 * 384 + 256 + f];
      float r = sig_fast(i1r + hr + br1);
      float z = sig_fast(i1z + hz + bz1);
      float nn = tanh_fast(i1n + bni1 + r * (hn + bnh1));
      h1 = (1.0f - z) * nn + z * h1;
      hb1[g2 * 136 + f] = (f16)h1;
    }
    __syncthreads();
  }

  h1s[g2 * 128 + f] = h1;
  __syncthreads();
  if (tid < 2 * C_) {
    int gg = tid / C_, c = tid - gg * C_;
    float s = bc[c];
    const float* wr = Wc + (size_t)c * 128;
    const float* hr = h1s + gg * 128;
    for (int k = 0; k < 128; k += 4) {
      float4 w = *(const float4*)(wr + k);
      s += hr[k] * w.x + hr[k + 1] * w.y + hr[k + 2] * w.z + hr[k + 3] * w.w;
    }
    out[(bid * 2 + gg) * C_ + c] = s;
  }
}

extern "C" void kernel_launch(void* const* d_in, const int* in_sizes, int n_in,
                              void* d_out, int out_size, void* d_ws, size_t ws_size,
                              hipStream_t stream) {
  const float* x    = (const float*)d_in[0];
  const int*   ei   = (const int*)d_in[1];
  const int*   batch= (const int*)d_in[2];
  const float* W1   = (const float*)d_in[3];
  const float* b1   = (const float*)d_in[4];
  const float* W2   = (const float*)d_in[5];
  const float* b2   = (const float*)d_in[6];
  const float* Wih0 = (const float*)d_in[7];
  const float* Whh0 = (const float*)d_in[8];
  const float* bih0 = (const float*)d_in[9];
  const float* bhh0 = (const float*)d_in[10];
  const float* Wih1 = (const float*)d_in[11];
  const float* Whh1 = (const float*)d_in[12];
  const float* bih1 = (const float*)d_in[13];
  const float* bhh1 = (const float*)d_in[14];
  const float* Wc   = (const float*)d_in[15];
  const float* bc   = (const float*)d_in[16];
  float* out = (float*)d_out;

  char* ws = (char*)d_ws;
  f16*   Xh    = (f16*)(ws + OFF_XH);
  f16*   A1    = (f16*)(ws + OFF_A1);
  f16*   H1    = (f16*)(ws + OFF_H1);
  f16*   A2    = A1;                 // A1 dead after GEMM1
  f16*   H2    = Xh;                 // Xh dead after AGG1
  int*   rec   = (int*)(ws + OFF_REC);
  float* dinv  = (float*)(ws + OFF_DINV);
  int*   rp    = (int*)(ws + OFF_RP);
  f16*   Wp    = (f16*)(ws + OFF_WP);
  int*   brp   = (int*)(ws + OFF_BRP);
  int*   blist = (int*)(ws + OFF_BLIST);
  f16*   embh  = (f16*)(ws + OFF_EMBH);
  f16*   gp    = (f16*)(ws + OFF_GPACK);
  float* gi0   = (float*)(ws + OFF_GI0);

  packall_kernel<<<896, 256, 0, stream>>>(W1, W2, Wp, Wih0, Whh0, Wih1, Whh1, gp);
  build_kernel<<<8, 1024, 0, stream>>>(ei, batch, rp, dinv, rec, brp, blist);
  cvt_kernel<<<10000, 256, 0, stream>>>(x, dinv, Xh);

  agg_kernel<<<20000, 256, 0, stream>>>(Xh, A1, rp, rec, dinv);
  gemm_kernel<<<1250, 256, 0, stream>>>(A1, Wp, b1, dinv, H1);
  agg_kernel<<<20000, 256, 0, stream>>>(H1, A2, rp, rec, dinv);
  gemm_kernel<<<1250, 256, 0, stream>>>(A2, Wp + 16384, b2, (const float*)nullptr, H2);

  pool_kernel<<<64, 256, 0, stream>>>(H2, brp, blist, embh);
  gi0_kernel<<<4, 256, 0, stream>>>(embh, gp, gi0);
  gru_fused<<<16, 256, 0, stream>>>(gp, gi0, bih0, bhh0, bih1, bhh1, Wc, bc, out);
}

// Round 9
// 338.354 us; speedup vs baseline: 1.3066x; 1.3066x over previous
//
#include <hip/hip_runtime.h>

#define T_ 8
#define N_ 10000
#define E_ 160000
#define G_ 32
#define C_ 10
#define F_ 128

typedef _Float16 f16;
typedef _Float16 f16x2 __attribute__((ext_vector_type(2)));
typedef _Float16 f16x4 __attribute__((ext_vector_type(4)));
typedef _Float16 f16x8 __attribute__((ext_vector_type(8)));
typedef float floatx4 __attribute__((ext_vector_type(4)));

static constexpr size_t ROWS = (size_t)T_ * N_;   // 80000
static constexpr int SLICE = E_ / 8;              // 20000 edges per (t, slice)

// ---------------- workspace layout (bytes) ----------------
// R9: CSR build = hist(64 blk) -> scan(9 blk) -> fill(64 blk); LDS atomics only.
static constexpr size_t OFF_XH    = 0;          // f16 [80000][128] X' = dinv*X (reused as H2)
static constexpr size_t OFF_A1    = 20480000;   // f16 [80000][128] (reused as A2)
static constexpr size_t OFF_H1    = 40960000;   // f16 [80000][128] H1' = dinv*H1
static constexpr size_t OFF_REC   = 61440000;   // int [T][E] src, grouped by dst
static constexpr size_t OFF_CNT   = 66560000;   // int [T][8][N] slice hist -> slice base
static constexpr size_t OFF_DINV  = 69120000;   // float [T][N]
static constexpr size_t OFF_RP    = 69440000;   // int [T][N+1]
static constexpr size_t OFF_CNTG  = 69760032;   // int [T*G]
static constexpr size_t OFF_BRP   = 69761056;   // int [T*G+1] (global positions)
static constexpr size_t OFF_WP    = 69762112;   // f16 packed W1,W2 (2*16384)
static constexpr size_t OFF_BLIST = 69827648;   // int [80000]
static constexpr size_t OFF_EMBH  = 70147648;   // f16 [256][128]
static constexpr size_t OFF_GPACK = 70213184;   // f16 4*49152 packed GRU weights
static constexpr size_t OFF_GI0   = 70606400;   // float [256][384]
// end ~71 MB

// ---------------- fast gates (v_exp_f32 / v_rcp_f32, ~1 ulp) ----------------
__device__ __forceinline__ float sig_fast(float x) {
  return __builtin_amdgcn_rcpf(1.0f + __builtin_amdgcn_exp2f(-1.4426950408889634f * x));
}
__device__ __forceinline__ float tanh_fast(float x) {
  return 1.0f - 2.0f * __builtin_amdgcn_rcpf(1.0f + __builtin_amdgcn_exp2f(2.8853900817779268f * x));
}

// ---------------- phase 1: per-(t,slice) degree histogram in LDS ----------------
__global__ __launch_bounds__(1024) void hist_kernel(const int* __restrict__ ei,
                                                    const int* __restrict__ batch,
                                                    int* __restrict__ cnt,
                                                    int* __restrict__ cntG) {
  __shared__ int hL[N_];                        // 40 KB
  __shared__ int cL[G_];
  int b = blockIdx.x, tid = threadIdx.x;
  int t = b & 7, s = b >> 3;                    // XCD-swizzled by t
  for (int i = tid; i < N_; i += 1024) hL[i] = 0;
  if (tid < G_) cL[tid] = 0;
  __syncthreads();
  const int* dstp = ei + (size_t)t * 2 * E_ + E_ + s * SLICE;
  for (int e4 = tid; e4 < SLICE / 4; e4 += 1024) {
    int4 d = *(const int4*)(dstp + e4 * 4);
    atomicAdd(&hL[d.x], 1); atomicAdd(&hL[d.y], 1);
    atomicAdd(&hL[d.z], 1); atomicAdd(&hL[d.w], 1);
  }
  if (s == 0)
    for (int n = tid; n < N_; n += 1024) atomicAdd(&cL[batch[t * N_ + n]], 1);
  __syncthreads();
  int* cp = cnt + ((size_t)t * 8 + s) * N_;
  for (int i = tid; i < N_; i += 1024) cp[i] = hL[i];
  if (s == 0 && tid < G_) cntG[t * G_ + tid] = cL[tid];
}

// ---------------- phase 2: per-t scan -> rp, dinv, in-place slice bases; blk8 -> brp ----------------
__global__ __launch_bounds__(1024) void scan_kernel(int* __restrict__ cnt,
                                                    int* __restrict__ rp,
                                                    float* __restrict__ dinv,
                                                    const int* __restrict__ cntG,
                                                    int* __restrict__ brp) {
  __shared__ int wsum[16];
  __shared__ int carry;
  int t = blockIdx.x, tid = threadIdx.x, lane = tid & 63, wid = tid >> 6;
  if (t == 8) {
    // 256-wide exclusive scan of group counts; per-t counts sum to N_, so the
    // global prefix directly equals t*N_ + within-t prefix.
    int v = (tid < 256) ? cntG[tid] : 0;
    for (int ofs = 1; ofs < 64; ofs <<= 1) {
      int u = __shfl_up(v, ofs);
      if (lane >= ofs) v += u;
    }
    if (lane == 63 && wid < 4) wsum[wid] = v;
    __syncthreads();
    if (tid < 256) {
      int base = 0;
      for (int w = 0; w < wid; ++w) base += wsum[w];
      if (tid == 0) brp[0] = 0;
      brp[tid + 1] = v + base;
    }
    return;
  }
  if (tid == 0) { carry = 0; rp[t * (N_ + 1)] = 0; }
  __syncthreads();
  for (int c0 = 0; c0 < N_; c0 += 1024) {
    int n = c0 + tid;
    int vs[8];
    int deg = 0;
    if (n < N_) {
#pragma unroll
      for (int s = 0; s < 8; ++s) {
        vs[s] = cnt[((size_t)t * 8 + s) * N_ + n];
        deg += vs[s];
      }
      dinv[t * N_ + n] = rsqrtf((float)deg + 1.0f);
    }
    int v = (n < N_) ? deg : 0;
    int v0 = v;
    for (int ofs = 1; ofs < 64; ofs <<= 1) {
      int u = __shfl_up(v, ofs);
      if (lane >= ofs) v += u;
    }
    if (lane == 63) wsum[wid] = v;
    __syncthreads();
    if (wid == 0) {
      int w = (lane < 16) ? wsum[lane] : 0;
      for (int ofs = 1; ofs < 16; ofs <<= 1) {
        int u = __shfl_up(w, ofs);
        if (lane >= ofs) w += u;
      }
      if (lane < 16) wsum[lane] = w;
    }
    __syncthreads();
    int base = carry + (wid ? wsum[wid - 1] : 0);
    if (n < N_) {
      rp[t * (N_ + 1) + n + 1] = base + v;
      int run = base + v - v0;                  // exclusive prefix = row start
#pragma unroll
      for (int s = 0; s < 8; ++s) {
        int vv = vs[s];
        cnt[((size_t)t * 8 + s) * N_ + n] = run;  // slice base, in place
        run += vv;
      }
    }
    __syncthreads();
    if (tid == 0) carry += wsum[15];
    __syncthreads();
  }
}

// ---------------- phase 3: per-(t,slice) placement via LDS running offsets ----------------
__global__ __launch_bounds__(1024) void fill_kernel(const int* __restrict__ ei,
                                                    const int* __restrict__ base,
                                                    int* __restrict__ rec,
                                                    const int* __restrict__ batch,
                                                    const int* __restrict__ brp,
                                                    int* __restrict__ blist) {
  __shared__ int offL[N_];                      // 40 KB running offsets
  __shared__ int cb[G_];
  int b = blockIdx.x, tid = threadIdx.x;
  int t = b & 7, s = b >> 3;
  const int* bp = base + ((size_t)t * 8 + s) * N_;
  for (int i = tid; i < N_; i += 1024) offL[i] = bp[i];
  if (s == 0 && tid < G_) cb[tid] = brp[t * G_ + tid];
  __syncthreads();
  const int* srcp = ei + (size_t)t * 2 * E_ + s * SLICE;
  const int* dstp = srcp + E_;
  int* rt = rec + (size_t)t * E_;
  for (int e4 = tid; e4 < SLICE / 4; e4 += 1024) {
    int4 sv = *(const int4*)(srcp + e4 * 4);
    int4 dv = *(const int4*)(dstp + e4 * 4);
    int p0 = atomicAdd(&offL[dv.x], 1);
    int p1 = atomicAdd(&offL[dv.y], 1);
    int p2 = atomicAdd(&offL[dv.z], 1);
    int p3 = atomicAdd(&offL[dv.w], 1);
    rt[p0] = sv.x; rt[p1] = sv.y; rt[p2] = sv.z; rt[p3] = sv.w;
  }
  if (s == 0) {
    for (int n = tid; n < N_; n += 1024) {
      int g = batch[t * N_ + n];
      int p = atomicAdd(&cb[g], 1);
      blist[p] = t * N_ + n;                    // brp holds global positions
    }
  }
}

// ---------------- fp32 -> fp16 convert, pre-scaled: X' = dinv[row] * x ----------------
__global__ void cvt_kernel(const float* __restrict__ x, const float* __restrict__ dinv,
                           f16* __restrict__ xh) {
  size_t i = ((size_t)blockIdx.x * 256 + threadIdx.x) * 4;
  float4 v = *(const float4*)(x + i);
  float d = dinv[i >> 7];
  f16x4 o; o.x = (f16)(v.x * d); o.y = (f16)(v.y * d);
  o.z = (f16)(v.z * d); o.w = (f16)(v.w * d);
  *(f16x4*)(xh + i) = o;
}

// ---------------- aggregation: out = dinv[row]*(sum X'[src] + X'[row]) ----------------
__global__ void agg_kernel(const f16* __restrict__ X, f16* __restrict__ A,
                           const int* __restrict__ rp, const int* __restrict__ rec,
                           const float* __restrict__ dinv) {
  int wave = threadIdx.x >> 6, lane = threadIdx.x & 63;
  int b = blockIdx.x;
  int t = b & 7, i = b >> 3;
  int n = i * 4 + wave;
  int row = t * N_ + n;
  float ds = dinv[row];
  f16x2 xv = *(const f16x2*)(X + (size_t)row * F_ + 2 * lane);
  float a00 = (float)xv.x, a01 = (float)xv.y;   // self term (X' already has one dinv)
  float a10 = 0.f, a11 = 0.f, a20 = 0.f, a21 = 0.f, a30 = 0.f, a31 = 0.f;
  int beg = rp[t * (N_ + 1) + n], end = rp[t * (N_ + 1) + n + 1];
  beg = __builtin_amdgcn_readfirstlane(beg);
  end = __builtin_amdgcn_readfirstlane(end);
  const int* rc = rec + (size_t)t * E_;
  const f16* Xt = X + (size_t)t * N_ * F_;
  int e = beg;
  int i0 = 0, i1 = 0, i2 = 0, i3 = 0;
  if (e + 3 < end) { i0 = rc[e]; i1 = rc[e + 1]; i2 = rc[e + 2]; i3 = rc[e + 3]; }
  for (; e + 7 < end; e += 4) {
    int n0 = rc[e + 4], n1 = rc[e + 5], n2 = rc[e + 6], n3 = rc[e + 7];
    f16x2 h0 = *(const f16x2*)(Xt + (size_t)i0 * F_ + 2 * lane);
    f16x2 h1 = *(const f16x2*)(Xt + (size_t)i1 * F_ + 2 * lane);
    f16x2 h2 = *(const f16x2*)(Xt + (size_t)i2 * F_ + 2 * lane);
    f16x2 h3 = *(const f16x2*)(Xt + (size_t)i3 * F_ + 2 * lane);
    a00 += (float)h0.x; a01 += (float)h0.y;
    a10 += (float)h1.x; a11 += (float)h1.y;
    a20 += (float)h2.x; a21 += (float)h2.y;
    a30 += (float)h3.x; a31 += (float)h3.y;
    i0 = n0; i1 = n1; i2 = n2; i3 = n3;
  }
  if (e + 3 < end) {
    f16x2 h0 = *(const f16x2*)(Xt + (size_t)i0 * F_ + 2 * lane);
    f16x2 h1 = *(const f16x2*)(Xt + (size_t)i1 * F_ + 2 * lane);
    f16x2 h2 = *(const f16x2*)(Xt + (size_t)i2 * F_ + 2 * lane);
    f16x2 h3 = *(const f16x2*)(Xt + (size_t)i3 * F_ + 2 * lane);
    a00 += (float)h0.x; a01 += (float)h0.y;
    a10 += (float)h1.x; a11 += (float)h1.y;
    a20 += (float)h2.x; a21 += (float)h2.y;
    a30 += (float)h3.x; a31 += (float)h3.y;
    e += 4;
  }
  for (; e < end; ++e) {
    int s = rc[e];
    f16x2 hv = *(const f16x2*)(Xt + (size_t)s * F_ + 2 * lane);
    a00 += (float)hv.x; a01 += (float)hv.y;
  }
  float r0 = ds * ((a00 + a10) + (a20 + a30));
  float r1 = ds * ((a01 + a11) + (a21 + a31));
  f16x2 o; o.x = (f16)r0; o.y = (f16)r1;
  *(f16x2*)(A + (size_t)row * F_ + 2 * lane) = o;
}

// ---------------- pack W1/W2 + GRU weights into MFMA B-frag layout (merged) ----------------
__global__ void packall_kernel(const float* __restrict__ W1, const float* __restrict__ W2,
                               f16* __restrict__ Wp,
                               const float* __restrict__ A0, const float* __restrict__ A1,
                               const float* __restrict__ A2, const float* __restrict__ A3,
                               f16* __restrict__ gp) {
  int idx = blockIdx.x * 256 + threadIdx.x;     // < 896*256 = 229376
  if (idx < 32768) {
    const float* W = (idx < 16384) ? W1 : W2;
    int l = idx & 16383;
    int j = l & 7, lane = (l >> 3) & 63, ct = (l >> 9) & 7, kc = (l >> 12) & 3;
    int k = kc * 32 + ((lane >> 4) & 3) * 8 + j;
    int n = ct * 16 + (lane & 15);
    Wp[idx] = (f16)W[k * 128 + n];
  } else {
    int gidx = idx - 32768;                     // < 196608
    int mat = gidx / 49152, l = gidx - mat * 49152;
    int j = l & 7, lane = (l >> 3) & 63, kc = (l >> 9) & 3, nt = l >> 11;
    int k = kc * 32 + ((lane >> 4) & 3) * 8 + j;
    int u = nt * 16 + (lane & 15);
    const float* W = (mat == 0) ? A0 : (mat == 1) ? A1 : (mat == 2) ? A2 : A3;
    gp[gidx] = (f16)W[u * 128 + k];
  }
}

// ---------------- GEMM: O = relu(A @ W + b) [* dinv-row scale], MFMA 16x16x32 ----------------
__global__ __launch_bounds__(256) void gemm_kernel(const f16* __restrict__ A,
                                                   const f16* __restrict__ Wp,
                                                   const float* __restrict__ bias,
                                                   const float* __restrict__ scale,
                                                   f16* __restrict__ O) {
  __shared__ f16x8 Bp[2048];                    // 32 KB packed W
  const f16x8* Wv = (const f16x8*)Wp;
  for (int i = threadIdx.x; i < 2048; i += 256) Bp[i] = Wv[i];
  __syncthreads();
  int wave = threadIdx.x >> 6, lane = threadIdx.x & 63;
  int quad = lane >> 4, m = lane & 15;
  int rowbase = blockIdx.x * 64 + wave * 16;
  const f16x8* Arow = (const f16x8*)(A + (size_t)(rowbase + m) * F_);
  floatx4 acc[8];
#pragma unroll
  for (int ct = 0; ct < 8; ++ct) { floatx4 z = {0.f, 0.f, 0.f, 0.f}; acc[ct] = z; }
#pragma unroll
  for (int kc = 0; kc < 4; ++kc) {
    f16x8 a = Arow[kc * 4 + quad];
#pragma unroll
    for (int ct = 0; ct < 8; ++ct)
      acc[ct] = __builtin_amdgcn_mfma_f32_16x16x32_f16(a, Bp[(kc * 8 + ct) * 64 + lane],
                                                       acc[ct], 0, 0, 0);
  }
  float sv[4];
#pragma unroll
  for (int r = 0; r < 4; ++r)
    sv[r] = scale ? scale[rowbase + quad * 4 + r] : 1.0f;
#pragma unroll
  for (int ct = 0; ct < 8; ++ct) {
    int colc = ct * 16 + m;
    float bv = bias[colc];
#pragma unroll
    for (int r = 0; r < 4; ++r) {
      int row = rowbase + quad * 4 + r;
      float v = fmaxf(acc[ct][r] + bv, 0.0f) * sv[r];
      O[(size_t)row * F_ + colc] = (f16)v;
    }
  }
}

// ---------------- pooling via batch-CSR gather -> f16 emb ----------------
__global__ void pool_kernel(const f16* __restrict__ H, const int* __restrict__ brp,
                            const int* __restrict__ blist, f16* __restrict__ embh) {
  int wave = threadIdx.x >> 6, lane = threadIdx.x & 63;
  int idx = blockIdx.x * 4 + wave;              // t*G+g, < 256
  int beg = brp[idx], end = brp[idx + 1];
  beg = __builtin_amdgcn_readfirstlane(beg);
  end = __builtin_amdgcn_readfirstlane(end);
  float a00 = 0.f, a01 = 0.f, a10 = 0.f, a11 = 0.f;
  float a20 = 0.f, a21 = 0.f, a30 = 0.f, a31 = 0.f;
  int e = beg;
  for (; e + 3 < end; e += 4) {
    int r0 = blist[e], r1 = blist[e + 1], r2 = blist[e + 2], r3 = blist[e + 3];
    f16x2 v0 = *(const f16x2*)(H + (size_t)r0 * F_ + 2 * lane);
    f16x2 v1 = *(const f16x2*)(H + (size_t)r1 * F_ + 2 * lane);
    f16x2 v2 = *(const f16x2*)(H + (size_t)r2 * F_ + 2 * lane);
    f16x2 v3 = *(const f16x2*)(H + (size_t)r3 * F_ + 2 * lane);
    a00 += (float)v0.x; a01 += (float)v0.y;
    a10 += (float)v1.x; a11 += (float)v1.y;
    a20 += (float)v2.x; a21 += (float)v2.y;
    a30 += (float)v3.x; a31 += (float)v3.y;
  }
  for (; e < end; ++e) {
    int r = blist[e];
    f16x2 v = *(const f16x2*)(H + (size_t)r * F_ + 2 * lane);
    a00 += (float)v.x; a01 += (float)v.y;
  }
  float d = 1.0f / fmaxf((float)(end - beg), 1.0f);
  f16x2 o;
  o.x = (f16)(((a00 + a10) + (a20 + a30)) * d);
  o.y = (f16)(((a01 + a11) + (a21 + a31)) * d);
  *(f16x2*)(embh + (size_t)idx * F_ + 2 * lane) = o;
}

// ---------------- gi0 = emb @ Wih0^T : M=256, K=128, N=384 ----------------
__global__ __launch_bounds__(256) void gi0_kernel(const f16* __restrict__ embh,
                                                  const f16* __restrict__ gp,
                                                  float* __restrict__ gi0) {
  int wave = threadIdx.x >> 6, lane = threadIdx.x & 63;
  int quad = lane >> 4, mm = lane & 15;
  int rowbase = blockIdx.x * 64 + wave * 16;    // grid 4
  const f16* Arow = embh + (size_t)(rowbase + mm) * 128;
  floatx4 acc[24];
#pragma unroll
  for (int nt = 0; nt < 24; ++nt) { floatx4 z = {0.f, 0.f, 0.f, 0.f}; acc[nt] = z; }
#pragma unroll
  for (int kc = 0; kc < 4; ++kc) {
    f16x8 a = *(const f16x8*)(Arow + kc * 32 + quad * 8);
#pragma unroll
    for (int nt = 0; nt < 24; ++nt) {
      f16x8 b = *(const f16x8*)(gp + (size_t)(((nt * 4 + kc) * 64 + lane)) * 8);
      acc[nt] = __builtin_amdgcn_mfma_f32_16x16x32_f16(a, b, acc[nt], 0, 0, 0);
    }
  }
#pragma unroll
  for (int nt = 0; nt < 24; ++nt)
#pragma unroll
    for (int r = 0; r < 4; ++r)
      gi0[(size_t)(rowbase + quad * 4 + r) * 384 + nt * 16 + mm] = acc[nt][r];
}

// ---------------- fused 2-layer GRU + final linear: 16 blocks x 2 groups ----------------
__global__ __launch_bounds__(256, 1) void gru_fused(
    const f16* __restrict__ gp, const float* __restrict__ gi0,
    const float* __restrict__ bih0, const float* __restrict__ bhh0,
    const float* __restrict__ bih1, const float* __restrict__ bhh1,
    const float* __restrict__ Wc, const float* __restrict__ bc,
    float* __restrict__ out) {
  __shared__ f16 hb0[16 * 136];
  __shared__ f16 hb1[16 * 136];
  __shared__ float ghb[2 * 384];
  __shared__ float gib[2 * 384];
  __shared__ float h1s[2 * 128];
  int tid = threadIdx.x, wave = tid >> 6, lane = tid & 63;
  int quad = lane >> 4, mm = lane & 15;
  int g2 = tid >> 7, f = tid & 127;
  int bid = blockIdx.x;

  f16x8 B0[24], B1[24];
#pragma unroll
  for (int i = 0; i < 6; ++i)
#pragma unroll
    for (int kc = 0; kc < 4; ++kc) {
      size_t off = (size_t)((((wave * 6 + i) * 4 + kc) * 64 + lane)) * 8;
      B0[i * 4 + kc] = *(const f16x8*)(gp + 1 * 49152 + off);
      B1[i * 4 + kc] = *(const f16x8*)(gp + 3 * 49152 + off);
    }
  float br0 = bih0[f] + bhh0[f];
  float bz0 = bih0[128 + f] + bhh0[128 + f];
  float bni0 = bih0[256 + f], bnh0 = bhh0[256 + f];
  float br1 = bih1[f] + bhh1[f];
  float bz1 = bih1[128 + f] + bhh1[128 + f];
  float bni1 = bih1[256 + f], bnh1 = bhh1[256 + f];

  for (int i = tid; i < 16 * 136; i += 256) { hb0[i] = (f16)0.f; hb1[i] = (f16)0.f; }
  float h0 = 0.f, h1 = 0.f;
  __syncthreads();

  const f16* wih1 = gp + 2 * 49152;
  for (int t = 0; t < T_; ++t) {
    f16x8 Bs[24];
#pragma unroll
    for (int i = 0; i < 6; ++i)
#pragma unroll
      for (int kc = 0; kc < 4; ++kc)
        Bs[i * 4 + kc] = *(const f16x8*)(wih1 +
            (size_t)((((wave * 6 + i) * 4 + kc) * 64 + lane)) * 8);
    const float* gi = gi0 + (size_t)(t * G_ + bid * 2 + g2) * 384;
    float gir = gi[f], giz = gi[128 + f], gin = gi[256 + f];

    floatx4 acc[6];
#pragma unroll
    for (int i = 0; i < 6; ++i) { floatx4 z = {0.f, 0.f, 0.f, 0.f}; acc[i] = z; }
#pragma unroll
    for (int kc = 0; kc < 4; ++kc) {
      f16x8 a = *(const f16x8*)(hb0 + mm * 136 + kc * 32 + quad * 8);
#pragma unroll
      for (int i = 0; i < 6; ++i)
        acc[i] = __builtin_amdgcn_mfma_f32_16x16x32_f16(a, B0[i * 4 + kc], acc[i], 0, 0, 0);
    }
    if (quad == 0) {
#pragma unroll
      for (int i = 0; i < 6; ++i) {
        ghb[0 * 384 + wave * 96 + i * 16 + mm] = acc[i][0];
        ghb[1 * 384 + wave * 96 + i * 16 + mm] = acc[i][1];
      }
    }
    __syncthreads();

    {
      float hr = ghb[g2 * 384 + f];
      float hz = ghb[g2 * 384 + 128 + f];
      float hn = ghb[g2 * 384 + 256 + f];
      float r = sig_fast(gir + hr + br0);
      float z = sig_fast(giz + hz + bz0);
      float nn = tanh_fast(gin + bni0 + r * (hn + bnh0));
      h0 = (1.0f - z) * nn + z * h0;
      hb0[g2 * 136 + f] = (f16)h0;
    }
    __syncthreads();

    floatx4 accx[6], acch[6];
#pragma unroll
    for (int i = 0; i < 6; ++i) {
      floatx4 z = {0.f, 0.f, 0.f, 0.f}; accx[i] = z; acch[i] = z;
    }
#pragma unroll
    for (int kc = 0; kc < 4; ++kc) {
      f16x8 ax = *(const f16x8*)(hb0 + mm * 136 + kc * 32 + quad * 8);
      f16x8 ah = *(const f16x8*)(hb1 + mm * 136 + kc * 32 + quad * 8);
#pragma unroll
      for (int i = 0; i < 6; ++i) {
        accx[i] = __builtin_amdgcn_mfma_f32_16x16x32_f16(ax, Bs[i * 4 + kc], accx[i], 0, 0, 0);
        acch[i] = __builtin_amdgcn_mfma_f32_16x16x32_f16(ah, B1[i * 4 + kc], acch[i], 0, 0, 0);
      }
    }
    if (quad == 0) {
#pragma unroll
      for (int i = 0; i < 6; ++i) {
        gib[0 * 384 + wave * 96 + i * 16 + mm] = accx[i][0];
        gib[1 * 384 + wave * 96 + i * 16 + mm] = accx[i][1];
        ghb[0 * 384 + wave * 96 + i * 16 + mm] = acch[i][0];
        ghb[1 * 384 + wave * 96 + i * 16 + mm] = acch[i][1];
      }
    }
    __syncthreads();

    {
      float i1r = gib[g2 * 384 + f];
      float i1z = gib[g2 * 384 + 128 + f];
      float i1n = gib[g2 * 384 + 256 + f];
      float hr = ghb[g2 * 384 + f];
      float hz = ghb[g2 * 384 + 128 + f];
      float hn = ghb[g2 * 384 + 256 + f];
      float r = sig_fast(i1r + hr + br1);
      float z = sig_fast(i1z + hz + bz1);
      float nn = tanh_fast(i1n + bni1 + r * (hn + bnh1));
      h1 = (1.0f - z) * nn + z * h1;
      hb1[g2 * 136 + f] = (f16)h1;
    }
    __syncthreads();
  }

  h1s[g2 * 128 + f] = h1;
  __syncthreads();
  if (tid < 2 * C_) {
    int gg = tid / C_, c = tid - gg * C_;
    float s = bc[c];
    const float* wr = Wc + (size_t)c * 128;
    const float* hr = h1s + gg * 128;
    for (int k = 0; k < 128; k += 4) {
      float4 w = *(const float4*)(wr + k);
      s += hr[k] * w.x + hr[k + 1] * w.y + hr[k + 2] * w.z + hr[k + 3] * w.w;
    }
    out[(bid * 2 + gg) * C_ + c] = s;
  }
}

extern "C" void kernel_launch(void* const* d_in, const int* in_sizes, int n_in,
                              void* d_out, int out_size, void* d_ws, size_t ws_size,
                              hipStream_t stream) {
  const float* x    = (const float*)d_in[0];
  const int*   ei   = (const int*)d_in[1];
  const int*   batch= (const int*)d_in[2];
  const float* W1   = (const float*)d_in[3];
  const float* b1   = (const float*)d_in[4];
  const float* W2   = (const float*)d_in[5];
  const float* b2   = (const float*)d_in[6];
  const float* Wih0 = (const float*)d_in[7];
  const float* Whh0 = (const float*)d_in[8];
  const float* bih0 = (const float*)d_in[9];
  const float* bhh0 = (const float*)d_in[10];
  const float* Wih1 = (const float*)d_in[11];
  const float* Whh1 = (const float*)d_in[12];
  const float* bih1 = (const float*)d_in[13];
  const float* bhh1 = (const float*)d_in[14];
  const float* Wc   = (const float*)d_in[15];
  const float* bc   = (const float*)d_in[16];
  float* out = (float*)d_out;

  char* ws = (char*)d_ws;
  f16*   Xh    = (f16*)(ws + OFF_XH);
  f16*   A1    = (f16*)(ws + OFF_A1);
  f16*   H1    = (f16*)(ws + OFF_H1);
  f16*   A2    = A1;                 // A1 dead after GEMM1
  f16*   H2    = Xh;                 // Xh dead after AGG1
  int*   rec   = (int*)(ws + OFF_REC);
  int*   cnt   = (int*)(ws + OFF_CNT);
  float* dinv  = (float*)(ws + OFF_DINV);
  int*   rp    = (int*)(ws + OFF_RP);
  int*   cntG  = (int*)(ws + OFF_CNTG);
  int*   brp   = (int*)(ws + OFF_BRP);
  f16*   Wp    = (f16*)(ws + OFF_WP);
  int*   blist = (int*)(ws + OFF_BLIST);
  f16*   embh  = (f16*)(ws + OFF_EMBH);
  f16*   gp    = (f16*)(ws + OFF_GPACK);
  float* gi0   = (float*)(ws + OFF_GI0);

  packall_kernel<<<896, 256, 0, stream>>>(W1, W2, Wp, Wih0, Whh0, Wih1, Whh1, gp);
  hist_kernel<<<64, 1024, 0, stream>>>(ei, batch, cnt, cntG);
  scan_kernel<<<9, 1024, 0, stream>>>(cnt, rp, dinv, cntG, brp);
  cvt_kernel<<<10000, 256, 0, stream>>>(x, dinv, Xh);
  fill_kernel<<<64, 1024, 0, stream>>>(ei, cnt, rec, batch, brp, blist);

  agg_kernel<<<20000, 256, 0, stream>>>(Xh, A1, rp, rec, dinv);
  gemm_kernel<<<1250, 256, 0, stream>>>(A1, Wp, b1, dinv, H1);
  agg_kernel<<<20000, 256, 0, stream>>>(H1, A2, rp, rec, dinv);
  gemm_kernel<<<1250, 256, 0, stream>>>(A2, Wp + 16384, b2, (const float*)nullptr, H2);

  pool_kernel<<<64, 256, 0, stream>>>(H2, brp, blist, embh);
  gi0_kernel<<<4, 256, 0, stream>>>(embh, gp, gi0);
  gru_fused<<<16, 256, 0, stream>>>(gp, gi0, bih0, bhh0, bih1, bhh1, Wc, bc, out);
}

// Round 10
// 309.343 us; speedup vs baseline: 1.4291x; 1.0938x over previous
//
#include <hip/hip_runtime.h>

#define T_ 8
#define N_ 10000
#define E_ 160000
#define G_ 32
#define C_ 10
#define F_ 128

typedef _Float16 f16;
typedef _Float16 f16x2 __attribute__((ext_vector_type(2)));
typedef _Float16 f16x4 __attribute__((ext_vector_type(4)));
typedef _Float16 f16x8 __attribute__((ext_vector_type(8)));
typedef float floatx4 __attribute__((ext_vector_type(4)));

static constexpr size_t ROWS = (size_t)T_ * N_;   // 80000
static constexpr int SLICE = E_ / 8;              // 20000 edges per (t, slice)

// ---------------- workspace layout (bytes) ----------------
static constexpr size_t OFF_XH    = 0;          // f16 [80000][128] X' = dinv*X (reused as H2)
static constexpr size_t OFF_A1    = 20480000;   // f16 [80000][128] (reused as A2)
static constexpr size_t OFF_H1    = 40960000;   // f16 [80000][128] H1' = dinv*H1
static constexpr size_t OFF_REC   = 61440000;   // int [T][E] src, grouped by dst
static constexpr size_t OFF_CNT   = 66560000;   // int [T][8][N] slice hist -> slice base
static constexpr size_t OFF_DINV  = 69120000;   // float [T][N]
static constexpr size_t OFF_RP    = 69440000;   // int [T][N+1]
static constexpr size_t OFF_CNTG  = 69760032;   // int [T*G]
static constexpr size_t OFF_BRP   = 69761056;   // int [T*G+1] (global positions)
static constexpr size_t OFF_WP    = 69762112;   // f16 packed W1,W2 (2*16384)
static constexpr size_t OFF_BLIST = 69827648;   // int [80000]
static constexpr size_t OFF_EMBH  = 70147648;   // f16 [256][128]
static constexpr size_t OFF_GPACK = 70213184;   // f16 4*49152 packed GRU weights
static constexpr size_t OFF_GI0   = 70606400;   // float [256][384]
static constexpr size_t OFF_PART  = 70999616;   // float [256][8][128] pool partials
// end ~72 MB

// ---------------- fast gates (v_exp_f32 / v_rcp_f32, ~1 ulp) ----------------
__device__ __forceinline__ float sig_fast(float x) {
  return __builtin_amdgcn_rcpf(1.0f + __builtin_amdgcn_exp2f(-1.4426950408889634f * x));
}
__device__ __forceinline__ float tanh_fast(float x) {
  return 1.0f - 2.0f * __builtin_amdgcn_rcpf(1.0f + __builtin_amdgcn_exp2f(2.8853900817779268f * x));
}

// ---------------- phase 1: per-(t,slice) degree histogram in LDS ----------------
__global__ __launch_bounds__(1024) void hist_kernel(const int* __restrict__ ei,
                                                    const int* __restrict__ batch,
                                                    int* __restrict__ cnt,
                                                    int* __restrict__ cntG) {
  __shared__ int hL[N_];                        // 40 KB
  __shared__ int cL[G_];
  int b = blockIdx.x, tid = threadIdx.x;
  int t = b & 7, s = b >> 3;                    // XCD-swizzled by t
  for (int i = tid; i < N_; i += 1024) hL[i] = 0;
  if (tid < G_) cL[tid] = 0;
  __syncthreads();
  const int* dstp = ei + (size_t)t * 2 * E_ + E_ + s * SLICE;
  for (int e4 = tid; e4 < SLICE / 4; e4 += 1024) {
    int4 d = *(const int4*)(dstp + e4 * 4);
    atomicAdd(&hL[d.x], 1); atomicAdd(&hL[d.y], 1);
    atomicAdd(&hL[d.z], 1); atomicAdd(&hL[d.w], 1);
  }
  if (s == 0)
    for (int n = tid; n < N_; n += 1024) atomicAdd(&cL[batch[t * N_ + n]], 1);
  __syncthreads();
  int* cp = cnt + ((size_t)t * 8 + s) * N_;
  for (int i = tid; i < N_; i += 1024) cp[i] = hL[i];
  if (s == 0 && tid < G_) cntG[t * G_ + tid] = cL[tid];
}

// ---------------- phase 2: per-t scan -> rp, dinv, in-place slice bases; blk8 -> brp ----------------
__global__ __launch_bounds__(1024) void scan_kernel(int* __restrict__ cnt,
                                                    int* __restrict__ rp,
                                                    float* __restrict__ dinv,
                                                    const int* __restrict__ cntG,
                                                    int* __restrict__ brp) {
  __shared__ int wsum[16];
  __shared__ int carry;
  int t = blockIdx.x, tid = threadIdx.x, lane = tid & 63, wid = tid >> 6;
  if (t == 8) {
    int v = (tid < 256) ? cntG[tid] : 0;
    for (int ofs = 1; ofs < 64; ofs <<= 1) {
      int u = __shfl_up(v, ofs);
      if (lane >= ofs) v += u;
    }
    if (lane == 63 && wid < 4) wsum[wid] = v;
    __syncthreads();
    if (tid < 256) {
      int base = 0;
      for (int w = 0; w < wid; ++w) base += wsum[w];
      if (tid == 0) brp[0] = 0;
      brp[tid + 1] = v + base;
    }
    return;
  }
  if (tid == 0) { carry = 0; rp[t * (N_ + 1)] = 0; }
  __syncthreads();
  for (int c0 = 0; c0 < N_; c0 += 1024) {
    int n = c0 + tid;
    int vs[8];
    int deg = 0;
    if (n < N_) {
#pragma unroll
      for (int s = 0; s < 8; ++s) {
        vs[s] = cnt[((size_t)t * 8 + s) * N_ + n];
        deg += vs[s];
      }
      dinv[t * N_ + n] = rsqrtf((float)deg + 1.0f);
    }
    int v = (n < N_) ? deg : 0;
    int v0 = v;
    for (int ofs = 1; ofs < 64; ofs <<= 1) {
      int u = __shfl_up(v, ofs);
      if (lane >= ofs) v += u;
    }
    if (lane == 63) wsum[wid] = v;
    __syncthreads();
    if (wid == 0) {
      int w = (lane < 16) ? wsum[lane] : 0;
      for (int ofs = 1; ofs < 16; ofs <<= 1) {
        int u = __shfl_up(w, ofs);
        if (lane >= ofs) w += u;
      }
      if (lane < 16) wsum[lane] = w;
    }
    __syncthreads();
    int base = carry + (wid ? wsum[wid - 1] : 0);
    if (n < N_) {
      rp[t * (N_ + 1) + n + 1] = base + v;
      int run = base + v - v0;
#pragma unroll
      for (int s = 0; s < 8; ++s) {
        int vv = vs[s];
        cnt[((size_t)t * 8 + s) * N_ + n] = run;
        run += vv;
      }
    }
    __syncthreads();
    if (tid == 0) carry += wsum[15];
    __syncthreads();
  }
}

// ---------------- phase 3: per-(t,slice) placement via LDS running offsets ----------------
__global__ __launch_bounds__(1024) void fill_kernel(const int* __restrict__ ei,
                                                    const int* __restrict__ base,
                                                    int* __restrict__ rec,
                                                    const int* __restrict__ batch,
                                                    const int* __restrict__ brp,
                                                    int* __restrict__ blist) {
  __shared__ int offL[N_];                      // 40 KB running offsets
  __shared__ int cb[G_];
  int b = blockIdx.x, tid = threadIdx.x;
  int t = b & 7, s = b >> 3;
  const int* bp = base + ((size_t)t * 8 + s) * N_;
  for (int i = tid; i < N_; i += 1024) offL[i] = bp[i];
  if (s == 0 && tid < G_) cb[tid] = brp[t * G_ + tid];
  __syncthreads();
  const int* srcp = ei + (size_t)t * 2 * E_ + s * SLICE;
  const int* dstp = srcp + E_;
  int* rt = rec + (size_t)t * E_;
  for (int e4 = tid; e4 < SLICE / 4; e4 += 1024) {
    int4 sv = *(const int4*)(srcp + e4 * 4);
    int4 dv = *(const int4*)(dstp + e4 * 4);
    int p0 = atomicAdd(&offL[dv.x], 1);
    int p1 = atomicAdd(&offL[dv.y], 1);
    int p2 = atomicAdd(&offL[dv.z], 1);
    int p3 = atomicAdd(&offL[dv.w], 1);
    rt[p0] = sv.x; rt[p1] = sv.y; rt[p2] = sv.z; rt[p3] = sv.w;
  }
  if (s == 0) {
    for (int n = tid; n < N_; n += 1024) {
      int g = batch[t * N_ + n];
      int p = atomicAdd(&cb[g], 1);
      blist[p] = t * N_ + n;
    }
  }
}

// ---------------- fp32 -> fp16 convert, pre-scaled: X' = dinv[row] * x ----------------
__global__ void cvt_kernel(const float* __restrict__ x, const float* __restrict__ dinv,
                           f16* __restrict__ xh) {
  size_t i = ((size_t)blockIdx.x * 256 + threadIdx.x) * 4;
  float4 v = *(const float4*)(x + i);
  float d = dinv[i >> 7];
  f16x4 o; o.x = (f16)(v.x * d); o.y = (f16)(v.y * d);
  o.z = (f16)(v.z * d); o.w = (f16)(v.w * d);
  *(f16x4*)(xh + i) = o;
}

// ---------------- aggregation: out = dinv[row]*(sum X'[src] + X'[row]) ----------------
__global__ void agg_kernel(const f16* __restrict__ X, f16* __restrict__ A,
                           const int* __restrict__ rp, const int* __restrict__ rec,
                           const float* __restrict__ dinv) {
  int wave = threadIdx.x >> 6, lane = threadIdx.x & 63;
  int b = blockIdx.x;
  int t = b & 7, i = b >> 3;
  int n = i * 4 + wave;
  int row = t * N_ + n;
  float ds = dinv[row];
  f16x2 xv = *(const f16x2*)(X + (size_t)row * F_ + 2 * lane);
  float a00 = (float)xv.x, a01 = (float)xv.y;
  float a10 = 0.f, a11 = 0.f, a20 = 0.f, a21 = 0.f, a30 = 0.f, a31 = 0.f;
  int beg = rp[t * (N_ + 1) + n], end = rp[t * (N_ + 1) + n + 1];
  beg = __builtin_amdgcn_readfirstlane(beg);
  end = __builtin_amdgcn_readfirstlane(end);
  const int* rc = rec + (size_t)t * E_;
  const f16* Xt = X + (size_t)t * N_ * F_;
  int e = beg;
  int i0 = 0, i1 = 0, i2 = 0, i3 = 0;
  if (e + 3 < end) { i0 = rc[e]; i1 = rc[e + 1]; i2 = rc[e + 2]; i3 = rc[e + 3]; }
  for (; e + 7 < end; e += 4) {
    int n0 = rc[e + 4], n1 = rc[e + 5], n2 = rc[e + 6], n3 = rc[e + 7];
    f16x2 h0 = *(const f16x2*)(Xt + (size_t)i0 * F_ + 2 * lane);
    f16x2 h1 = *(const f16x2*)(Xt + (size_t)i1 * F_ + 2 * lane);
    f16x2 h2 = *(const f16x2*)(Xt + (size_t)i2 * F_ + 2 * lane);
    f16x2 h3 = *(const f16x2*)(Xt + (size_t)i3 * F_ + 2 * lane);
    a00 += (float)h0.x; a01 += (float)h0.y;
    a10 += (float)h1.x; a11 += (float)h1.y;
    a20 += (float)h2.x; a21 += (float)h2.y;
    a30 += (float)h3.x; a31 += (float)h3.y;
    i0 = n0; i1 = n1; i2 = n2; i3 = n3;
  }
  if (e + 3 < end) {
    f16x2 h0 = *(const f16x2*)(Xt + (size_t)i0 * F_ + 2 * lane);
    f16x2 h1 = *(const f16x2*)(Xt + (size_t)i1 * F_ + 2 * lane);
    f16x2 h2 = *(const f16x2*)(Xt + (size_t)i2 * F_ + 2 * lane);
    f16x2 h3 = *(const f16x2*)(Xt + (size_t)i3 * F_ + 2 * lane);
    a00 += (float)h0.x; a01 += (float)h0.y;
    a10 += (float)h1.x; a11 += (float)h1.y;
    a20 += (float)h2.x; a21 += (float)h2.y;
    a30 += (float)h3.x; a31 += (float)h3.y;
    e += 4;
  }
  for (; e < end; ++e) {
    int s = rc[e];
    f16x2 hv = *(const f16x2*)(Xt + (size_t)s * F_ + 2 * lane);
    a00 += (float)hv.x; a01 += (float)hv.y;
  }
  float r0 = ds * ((a00 + a10) + (a20 + a30));
  float r1 = ds * ((a01 + a11) + (a21 + a31));
  f16x2 o; o.x = (f16)r0; o.y = (f16)r1;
  *(f16x2*)(A + (size_t)row * F_ + 2 * lane) = o;
}

// ---------------- pack W1/W2 + GRU weights into MFMA B-frag layout (merged) ----------------
__global__ void packall_kernel(const float* __restrict__ W1, const float* __restrict__ W2,
                               f16* __restrict__ Wp,
                               const float* __restrict__ A0, const float* __restrict__ A1,
                               const float* __restrict__ A2, const float* __restrict__ A3,
                               f16* __restrict__ gp) {
  int idx = blockIdx.x * 256 + threadIdx.x;     // < 896*256 = 229376
  if (idx < 32768) {
    const float* W = (idx < 16384) ? W1 : W2;
    int l = idx & 16383;
    int j = l & 7, lane = (l >> 3) & 63, ct = (l >> 9) & 7, kc = (l >> 12) & 3;
    int k = kc * 32 + ((lane >> 4) & 3) * 8 + j;
    int n = ct * 16 + (lane & 15);
    Wp[idx] = (f16)W[k * 128 + n];
  } else {
    int gidx = idx - 32768;                     // < 196608
    int mat = gidx / 49152, l = gidx - mat * 49152;
    int j = l & 7, lane = (l >> 3) & 63, kc = (l >> 9) & 3, nt = l >> 11;
    int k = kc * 32 + ((lane >> 4) & 3) * 8 + j;
    int u = nt * 16 + (lane & 15);
    const float* W = (mat == 0) ? A0 : (mat == 1) ? A1 : (mat == 2) ? A2 : A3;
    gp[gidx] = (f16)W[u * 128 + k];
  }
}

// ---------------- GEMM: O = relu(A @ W + b) [* dinv-row scale], MFMA 16x16x32 ----------------
__global__ __launch_bounds__(256) void gemm_kernel(const f16* __restrict__ A,
                                                   const f16* __restrict__ Wp,
                                                   const float* __restrict__ bias,
                                                   const float* __restrict__ scale,
                                                   f16* __restrict__ O) {
  __shared__ f16x8 Bp[2048];                    // 32 KB packed W
  const f16x8* Wv = (const f16x8*)Wp;
  for (int i = threadIdx.x; i < 2048; i += 256) Bp[i] = Wv[i];
  __syncthreads();
  int wave = threadIdx.x >> 6, lane = threadIdx.x & 63;
  int quad = lane >> 4, m = lane & 15;
  int rowbase = blockIdx.x * 64 + wave * 16;
  const f16x8* Arow = (const f16x8*)(A + (size_t)(rowbase + m) * F_);
  floatx4 acc[8];
#pragma unroll
  for (int ct = 0; ct < 8; ++ct) { floatx4 z = {0.f, 0.f, 0.f, 0.f}; acc[ct] = z; }
#pragma unroll
  for (int kc = 0; kc < 4; ++kc) {
    f16x8 a = Arow[kc * 4 + quad];
#pragma unroll
    for (int ct = 0; ct < 8; ++ct)
      acc[ct] = __builtin_amdgcn_mfma_f32_16x16x32_f16(a, Bp[(kc * 8 + ct) * 64 + lane],
                                                       acc[ct], 0, 0, 0);
  }
  float sv[4];
#pragma unroll
  for (int r = 0; r < 4; ++r)
    sv[r] = scale ? scale[rowbase + quad * 4 + r] : 1.0f;
#pragma unroll
  for (int ct = 0; ct < 8; ++ct) {
    int colc = ct * 16 + m;
    float bv = bias[colc];
#pragma unroll
    for (int r = 0; r < 4; ++r) {
      int row = rowbase + quad * 4 + r;
      float v = fmaxf(acc[ct][r] + bv, 0.0f) * sv[r];
      O[(size_t)row * F_ + colc] = (f16)v;
    }
  }
}

// ---------------- pool stage 1: one wave per (group, 1/8 slice) -> fp32 partials ----------------
__global__ void pool1_kernel(const f16* __restrict__ H, const int* __restrict__ brp,
                             const int* __restrict__ blist, float* __restrict__ part) {
  int b = blockIdx.x;                           // 512
  int wave = threadIdx.x >> 6, lane = threadIdx.x & 63;
  int idx = b >> 1;                             // t*G+g
  int s = (b & 1) * 4 + wave;                   // 0..7
  int beg = brp[idx], end = brp[idx + 1];
  beg = __builtin_amdgcn_readfirstlane(beg);
  end = __builtin_amdgcn_readfirstlane(end);
  int len = end - beg;
  int lo = beg + (int)(((long long)len * s) >> 3);
  int hi = beg + (int)(((long long)len * (s + 1)) >> 3);
  float a00 = 0.f, a01 = 0.f, a10 = 0.f, a11 = 0.f;
  float a20 = 0.f, a21 = 0.f, a30 = 0.f, a31 = 0.f;
  int e = lo;
  for (; e + 3 < hi; e += 4) {
    int r0 = blist[e], r1 = blist[e + 1], r2 = blist[e + 2], r3 = blist[e + 3];
    f16x2 v0 = *(const f16x2*)(H + (size_t)r0 * F_ + 2 * lane);
    f16x2 v1 = *(const f16x2*)(H + (size_t)r1 * F_ + 2 * lane);
    f16x2 v2 = *(const f16x2*)(H + (size_t)r2 * F_ + 2 * lane);
    f16x2 v3 = *(const f16x2*)(H + (size_t)r3 * F_ + 2 * lane);
    a00 += (float)v0.x; a01 += (float)v0.y;
    a10 += (float)v1.x; a11 += (float)v1.y;
    a20 += (float)v2.x; a21 += (float)v2.y;
    a30 += (float)v3.x; a31 += (float)v3.y;
  }
  for (; e < hi; ++e) {
    int r = blist[e];
    f16x2 v = *(const f16x2*)(H + (size_t)r * F_ + 2 * lane);
    a00 += (float)v.x; a01 += (float)v.y;
  }
  float2 o;
  o.x = (a00 + a10) + (a20 + a30);
  o.y = (a01 + a11) + (a21 + a31);
  *(float2*)(part + ((size_t)idx * 8 + s) * F_ + 2 * lane) = o;
}

// ---------------- pool stage 2: reduce 8 partials -> mean -> f16 emb ----------------
__global__ void pool2_kernel(const float* __restrict__ part, const int* __restrict__ brp,
                             f16* __restrict__ embh) {
  int idx = blockIdx.x * 2 + (threadIdx.x >> 7);   // grid 128
  int f = threadIdx.x & 127;
  float s = 0.f;
#pragma unroll
  for (int k = 0; k < 8; ++k) s += part[((size_t)idx * 8 + k) * F_ + f];
  int cnt = brp[idx + 1] - brp[idx];
  embh[(size_t)idx * F_ + f] = (f16)(s / fmaxf((float)cnt, 1.0f));
}

// ---------------- gi0 = emb @ Wih0^T : M=256, K=128, N=384 ----------------
__global__ __launch_bounds__(256) void gi0_kernel(const f16* __restrict__ embh,
                                                  const f16* __restrict__ gp,
                                                  float* __restrict__ gi0) {
  int wave = threadIdx.x >> 6, lane = threadIdx.x & 63;
  int quad = lane >> 4, mm = lane & 15;
  int rowbase = blockIdx.x * 64 + wave * 16;    // grid 4
  const f16* Arow = embh + (size_t)(rowbase + mm) * 128;
  floatx4 acc[24];
#pragma unroll
  for (int nt = 0; nt < 24; ++nt) { floatx4 z = {0.f, 0.f, 0.f, 0.f}; acc[nt] = z; }
#pragma unroll
  for (int kc = 0; kc < 4; ++kc) {
    f16x8 a = *(const f16x8*)(Arow + kc * 32 + quad * 8);
#pragma unroll
    for (int nt = 0; nt < 24; ++nt) {
      f16x8 b = *(const f16x8*)(gp + (size_t)(((nt * 4 + kc) * 64 + lane)) * 8);
      acc[nt] = __builtin_amdgcn_mfma_f32_16x16x32_f16(a, b, acc[nt], 0, 0, 0);
    }
  }
#pragma unroll
  for (int nt = 0; nt < 24; ++nt)
#pragma unroll
    for (int r = 0; r < 4; ++r)
      gi0[(size_t)(rowbase + quad * 4 + r) * 384 + nt * 16 + mm] = acc[nt][r];
}

// ---------------- fused 2-layer GRU + final linear: 16 blocks x 2 groups ----------------
__global__ __launch_bounds__(256, 1) void gru_fused(
    const f16* __restrict__ gp, const float* __restrict__ gi0,
    const float* __restrict__ bih0, const float* __restrict__ bhh0,
    const float* __restrict__ bih1, const float* __restrict__ bhh1,
    const float* __restrict__ Wc, const float* __restrict__ bc,
    float* __restrict__ out) {
  __shared__ f16 hb0[16 * 136];
  __shared__ f16 hb1[16 * 136];
  __shared__ float ghb[2 * 384];
  __shared__ float gib[2 * 384];
  __shared__ float h1s[2 * 128];
  int tid = threadIdx.x, wave = tid >> 6, lane = tid & 63;
  int quad = lane >> 4, mm = lane & 15;
  int g2 = tid >> 7, f = tid & 127;
  int bid = blockIdx.x;

  f16x8 B0[24], B1[24];
#pragma unroll
  for (int i = 0; i < 6; ++i)
#pragma unroll
    for (int kc = 0; kc < 4; ++kc) {
      size_t off = (size_t)((((wave * 6 + i) * 4 + kc) * 64 + lane)) * 8;
      B0[i * 4 + kc] = *(const f16x8*)(gp + 1 * 49152 + off);
      B1[i * 4 + kc] = *(const f16x8*)(gp + 3 * 49152 + off);
    }
  float br0 = bih0[f] + bhh0[f];
  float bz0 = bih0[128 + f] + bhh0[128 + f];
  float bni0 = bih0[256 + f], bnh0 = bhh0[256 + f];
  float br1 = bih1[f] + bhh1[f];
  float bz1 = bih1[128 + f] + bhh1[128 + f];
  float bni1 = bih1[256 + f], bnh1 = bhh1[256 + f];

  for (int i = tid; i < 16 * 136; i += 256) { hb0[i] = (f16)0.f; hb1[i] = (f16)0.f; }
  float h0 = 0.f, h1 = 0.f;
  __syncthreads();

  const f16* wih1 = gp + 2 * 49152;
  for (int t = 0; t < T_; ++t) {
    f16x8 Bs[24];
#pragma unroll
    for (int i = 0; i < 6; ++i)
#pragma unroll
      for (int kc = 0; kc < 4; ++kc)
        Bs[i * 4 + kc] = *(const f16x8*)(wih1 +
            (size_t)((((wave * 6 + i) * 4 + kc) * 64 + lane)) * 8);
    const float* gi = gi0 + (size_t)(t * G_ + bid * 2 + g2) * 384;
    float gir = gi[f], giz = gi[128 + f], gin = gi[256 + f];

    floatx4 acc[6];
#pragma unroll
    for (int i = 0; i < 6; ++i) { floatx4 z = {0.f, 0.f, 0.f, 0.f}; acc[i] = z; }
#pragma unroll
    for (int kc = 0; kc < 4; ++kc) {
      f16x8 a = *(const f16x8*)(hb0 + mm * 136 + kc * 32 + quad * 8);
#pragma unroll
      for (int i = 0; i < 6; ++i)
        acc[i] = __builtin_amdgcn_mfma_f32_16x16x32_f16(a, B0[i * 4 + kc], acc[i], 0, 0, 0);
    }
    if (quad == 0) {
#pragma unroll
      for (int i = 0; i < 6; ++i) {
        ghb[0 * 384 + wave * 96 + i * 16 + mm] = acc[i][0];
        ghb[1 * 384 + wave * 96 + i * 16 + mm] = acc[i][1];
      }
    }
    __syncthreads();

    {
      float hr = ghb[g2 * 384 + f];
      float hz = ghb[g2 * 384 + 128 + f];
      float hn = ghb[g2 * 384 + 256 + f];
      float r = sig_fast(gir + hr + br0);
      float z = sig_fast(giz + hz + bz0);
      float nn = tanh_fast(gin + bni0 + r * (hn + bnh0));
      h0 = (1.0f - z) * nn + z * h0;
      hb0[g2 * 136 + f] = (f16)h0;
    }
    __syncthreads();

    floatx4 accx[6], acch[6];
#pragma unroll
    for (int i = 0; i < 6; ++i) {
      floatx4 z = {0.f, 0.f, 0.f, 0.f}; accx[i] = z; acch[i] = z;
    }
#pragma unroll
    for (int kc = 0; kc < 4; ++kc) {
      f16x8 ax = *(const f16x8*)(hb0 + mm * 136 + kc * 32 + quad * 8);
      f16x8 ah = *(const f16x8*)(hb1 + mm * 136 + kc * 32 + quad * 8);
#pragma unroll
      for (int i = 0; i < 6; ++i) {
        accx[i] = __builtin_amdgcn_mfma_f32_16x16x32_f16(ax, Bs[i * 4 + kc], accx[i], 0, 0, 0);
        acch[i] = __builtin_amdgcn_mfma_f32_16x16x32_f16(ah, B1[i * 4 + kc], acch[i], 0, 0, 0);
      }
    }
    if (quad == 0) {
#pragma unroll
      for (int i = 0; i < 6; ++i) {
        gib[0 * 384 + wave * 96 + i * 16 + mm] = accx[i][0];
        gib[1 * 384 + wave * 96 + i * 16 + mm] = accx[i][1];
        ghb[0 * 384 + wave * 96 + i * 16 + mm] = acch[i][0];
        ghb[1 * 384 + wave * 96 + i * 16 + mm] = acch[i][1];
      }
    }
    __syncthreads();

    {
      float i1r = gib[g2 * 384 + f];
      float i1z = gib[g2 * 384 + 128 + f];
      float i1n = gib[g2 * 384 + 256 + f];
      float hr = ghb[g2 * 384 + f];
      float hz = ghb[g2 * 384 + 128 + f];
      float hn = ghb[g2 * 384 + 256 + f];
      float r = sig_fast(i1r + hr + br1);
      float z = sig_fast(i1z + hz + bz1);
      float nn = tanh_fast(i1n + bni1 + r * (hn + bnh1));
      h1 = (1.0f - z) * nn + z * h1;
      hb1[g2 * 136 + f] = (f16)h1;
    }
    __syncthreads();
  }

  h1s[g2 * 128 + f] = h1;
  __syncthreads();
  if (tid < 2 * C_) {
    int gg = tid / C_, c = tid - gg * C_;
    float s = bc[c];
    const float* wr = Wc + (size_t)c * 128;
    const float* hr = h1s + gg * 128;
    for (int k = 0; k < 128; k += 4) {
      float4 w = *(const float4*)(wr + k);
      s += hr[k] * w.x + hr[k + 1] * w.y + hr[k + 2] * w.z + hr[k + 3] * w.w;
    }
    out[(bid * 2 + gg) * C_ + c] = s;
  }
}

extern "C" void kernel_launch(void* const* d_in, const int* in_sizes, int n_in,
                              void* d_out, int out_size, void* d_ws, size_t ws_size,
                              hipStream_t stream) {
  const float* x    = (const float*)d_in[0];
  const int*   ei   = (const int*)d_in[1];
  const int*   batch= (const int*)d_in[2];
  const float* W1   = (const float*)d_in[3];
  const float* b1   = (const float*)d_in[4];
  const float* W2   = (const float*)d_in[5];
  const float* b2   = (const float*)d_in[6];
  const float* Wih0 = (const float*)d_in[7];
  const float* Whh0 = (const float*)d_in[8];
  const float* bih0 = (const float*)d_in[9];
  const float* bhh0 = (const float*)d_in[10];
  const float* Wih1 = (const float*)d_in[11];
  const float* Whh1 = (const float*)d_in[12];
  const float* bih1 = (const float*)d_in[13];
  const float* bhh1 = (const float*)d_in[14];
  const float* Wc   = (const float*)d_in[15];
  const float* bc   = (const float*)d_in[16];
  float* out = (float*)d_out;

  char* ws = (char*)d_ws;
  f16*   Xh    = (f16*)(ws + OFF_XH);
  f16*   A1    = (f16*)(ws + OFF_A1);
  f16*   H1    = (f16*)(ws + OFF_H1);
  f16*   A2    = A1;                 // A1 dead after GEMM1
  f16*   H2    = Xh;                 // Xh dead after AGG1
  int*   rec   = (int*)(ws + OFF_REC);
  int*   cnt   = (int*)(ws + OFF_CNT);
  float* dinv  = (float*)(ws + OFF_DINV);
  int*   rp    = (int*)(ws + OFF_RP);
  int*   cntG  = (int*)(ws + OFF_CNTG);
  int*   brp   = (int*)(ws + OFF_BRP);
  f16*   Wp    = (f16*)(ws + OFF_WP);
  int*   blist = (int*)(ws + OFF_BLIST);
  f16*   embh  = (f16*)(ws + OFF_EMBH);
  f16*   gp    = (f16*)(ws + OFF_GPACK);
  float* gi0   = (float*)(ws + OFF_GI0);
  float* part  = (float*)(ws + OFF_PART);

  packall_kernel<<<896, 256, 0, stream>>>(W1, W2, Wp, Wih0, Whh0, Wih1, Whh1, gp);
  hist_kernel<<<64, 1024, 0, stream>>>(ei, batch, cnt, cntG);
  scan_kernel<<<9, 1024, 0, stream>>>(cnt, rp, dinv, cntG, brp);
  cvt_kernel<<<10000, 256, 0, stream>>>(x, dinv, Xh);
  fill_kernel<<<64, 1024, 0, stream>>>(ei, cnt, rec, batch, brp, blist);

  agg_kernel<<<20000, 256, 0, stream>>>(Xh, A1, rp, rec, dinv);
  gemm_kernel<<<1250, 256, 0, stream>>>(A1, Wp, b1, dinv, H1);
  agg_kernel<<<20000, 256, 0, stream>>>(H1, A2, rp, rec, dinv);
  gemm_kernel<<<1250, 256, 0, stream>>>(A2, Wp + 16384, b2, (const float*)nullptr, H2);

  pool1_kernel<<<512, 256, 0, stream>>>(H2, brp, blist, part);
  pool2_kernel<<<128, 256, 0, stream>>>(part, brp, embh);
  gi0_kernel<<<4, 256, 0, stream>>>(embh, gp, gi0);
  gru_fused<<<16, 256, 0, stream>>>(gp, gi0, bih0, bhh0, bih1, bhh1, Wc, bc, out);
}